// Round 4
// baseline (357.139 us; speedup 1.0000x reference)
//
#include <hip/hip_runtime.h>

#define RES 128
#define RES_V 129
#define N_VOX 400000

constexpr int N_VERTS = RES_V * RES_V * RES_V;   // 2146689
constexpr int N_CELLS = RES * RES * RES;         // 2097152
constexpr long VOUT_WORDS = (long)N_VERTS * 10;  // 21466890
constexpr long OUTW_WORDS = (long)N_CELLS * 21;  // 44040192
constexpr int SCAN_BLOCKS = 512;                 // N_CELLS / 4096
constexpr float SDF_BIAS = -1.0f / 128.0f;
constexpr float DEFORM_SCALE = (float)((1.0 - 1e-8) / 256.0);
constexpr float INV_RES = 1.0f / 128.0f;

// --- K0: init hist + lastidx ---
__global__ void init_kernel(unsigned int* __restrict__ counts,
                            int* __restrict__ lastidx)
{
    int t = blockIdx.x * blockDim.x + threadIdx.x;
    if (t < N_CELLS) { counts[t] = 0u; lastidx[t] = -1; }
}

// --- K1: per-voxel cell histogram + last-wins index ---
__global__ void count_kernel(const int* __restrict__ coords,
                             unsigned int* __restrict__ counts,
                             int* __restrict__ lastidx)
{
    int n = blockIdx.x * blockDim.x + threadIdx.x;
    if (n >= N_VOX) return;
    int cx = coords[n * 3 + 0];
    int cy = coords[n * 3 + 1];
    int cz = coords[n * 3 + 2];
    int cid = (cx * RES + cy) * RES + cz;
    atomicAdd(counts + cid, 1u);
    atomicMax(lastidx + cid, n);   // numpy .at[].set duplicate = last write wins
}

// --- K2: block-local exclusive scan (4096 elems / block) -> starts(local) ---
__global__ void scan1_kernel(const unsigned int* __restrict__ counts,
                             unsigned int* __restrict__ starts,
                             unsigned int* __restrict__ blocksums)
{
    __shared__ unsigned int part[256];
    int b = blockIdx.x, t = threadIdx.x;
    long base = (long)b * 4096 + (long)t * 16;
    unsigned int v[16], s = 0;
#pragma unroll
    for (int i = 0; i < 16; ++i) { v[i] = counts[base + i]; s += v[i]; }
    part[t] = s;
    __syncthreads();
    for (int off = 1; off < 256; off <<= 1) {
        unsigned int x = (t >= off) ? part[t - off] : 0u;
        __syncthreads();
        part[t] += x;
        __syncthreads();
    }
    unsigned int excl = (t == 0) ? 0u : part[t - 1];
    if (t == 255) blocksums[b] = part[255];
    unsigned int run = excl;
#pragma unroll
    for (int i = 0; i < 16; ++i) { starts[base + i] = run; run += v[i]; }
}

// --- K3: exclusive scan of the 512 block sums (single block) ---
__global__ void scan2_kernel(unsigned int* __restrict__ blocksums)
{
    __shared__ unsigned int sh[SCAN_BLOCKS];
    int t = threadIdx.x;
    sh[t] = blocksums[t];
    __syncthreads();
    for (int off = 1; off < SCAN_BLOCKS; off <<= 1) {
        unsigned int x = (t >= off) ? sh[t - off] : 0u;
        __syncthreads();
        sh[t] += x;
        __syncthreads();
    }
    blocksums[t] = (t == 0) ? 0u : sh[t - 1];
}

// --- K4: globalize starts, copy to cursors (reuse counts), cap sentinel ---
__global__ void fixup_kernel(unsigned int* __restrict__ starts,
                             unsigned int* __restrict__ cursors,  // = counts reused
                             const unsigned int* __restrict__ blocksums)
{
    int t = blockIdx.x * blockDim.x + threadIdx.x;
    if (t >= N_CELLS) return;
    unsigned int g = starts[t] + blocksums[t >> 12];
    starts[t] = g;
    cursors[t] = g;
    if (t == 0) starts[N_CELLS] = (unsigned int)N_VOX;
}

// --- K5: fill CSR list ---
__global__ void fill_kernel(const int* __restrict__ coords,
                            unsigned int* __restrict__ cursors,
                            unsigned int* __restrict__ list)
{
    int n = blockIdx.x * blockDim.x + threadIdx.x;
    if (n >= N_VOX) return;
    int cx = coords[n * 3 + 0];
    int cy = coords[n * 3 + 1];
    int cz = coords[n * 3 + 2];
    int cid = (cx * RES + cy) * RES + cz;
    unsigned int slot = atomicAdd(cursors + cid, 1u);
    list[slot] = (unsigned int)n;
}

// --- K6: 3D-tiled per-vertex gather + mean + finalize ---
// block = 8x8x8 vertices (z fastest); grid = 17^3. All 8 corner-visits to a
// voxel row occur within one/adjacent blocks -> feats rows fetched ~once.
__global__ void gather_finalize_tiled(const float* __restrict__ feats,
                                      const unsigned int* __restrict__ starts,
                                      const unsigned int* __restrict__ list,
                                      float* __restrict__ vout)
{
    int z = blockIdx.x * 8 + threadIdx.x;
    int y = blockIdx.y * 8 + threadIdx.y;
    int x = blockIdx.z * 8 + threadIdx.z;
    if (x >= RES_V || y >= RES_V || z >= RES_V) return;

    float sums[10];
#pragma unroll
    for (int j = 0; j < 10; ++j) sums[j] = 0.0f;
    int cnt = 0;

#pragma unroll
    for (int dx = 0; dx < 2; ++dx) {
        int cx = x - dx;
        if (cx < 0 || cx >= RES) continue;
#pragma unroll
        for (int dy = 0; dy < 2; ++dy) {
            int cy = y - dy;
            if (cy < 0 || cy >= RES) continue;
#pragma unroll
            for (int dz = 0; dz < 2; ++dz) {
                int cz = z - dz;
                if (cz < 0 || cz >= RES) continue;
                int cid = (cx * RES + cy) * RES + cz;
                unsigned int s = starts[cid];
                unsigned int e = starts[cid + 1];
                if (s == e) continue;
                int cidx = dx + 2 * dy + 4 * dz;
                for (unsigned int i = s; i < e; ++i) {
                    int n = (int)list[i];
                    const float* f = feats + (long)n * 101;
                    sums[0] += f[cidx];
#pragma unroll
                    for (int k = 0; k < 3; ++k) sums[1 + k] += f[8 + 3 * cidx + k];
#pragma unroll
                    for (int k = 0; k < 6; ++k) sums[4 + k] += f[53 + 6 * cidx + k];
                }
                cnt += (int)(e - s);
            }
        }
    }

    float fc = (float)cnt;
    float inv = 1.0f / fmaxf(fc, 1.0f);
    float o[10];
    o[0] = (float)x * INV_RES - 0.5f + DEFORM_SCALE * tanhf(sums[1] * inv);
    o[1] = (float)y * INV_RES - 0.5f + DEFORM_SCALE * tanhf(sums[2] * inv);
    o[2] = (float)z * INV_RES - 0.5f + DEFORM_SCALE * tanhf(sums[3] * inv);
    o[3] = (sums[0] + fc * SDF_BIAS) * inv;
#pragma unroll
    for (int j = 0; j < 6; ++j) o[4 + j] = sums[4 + j] * inv;

    int vid = (x * RES_V + y) * RES_V + z;
    float* p = vout + (long)vid * 10;
#pragma unroll
    for (int j = 0; j < 10; ++j) p[j] = o[j];
}

// --- K7: weights grid, one thread per output element (coalesced) ---
__global__ void weights_fill(const float* __restrict__ feats,
                             const int* __restrict__ lastidx,
                             float* __restrict__ outw)
{
    long t = (long)blockIdx.x * blockDim.x + threadIdx.x;
    if (t >= OUTW_WORDS) return;
    int cid = (int)(t / 21);
    int j = (int)(t - (long)cid * 21);
    int li = lastidx[cid];
    float val = 0.0f;
    if (li >= 0) val = feats[(long)li * 101 + 32 + j];
    outw[t] = val;
}

extern "C" void kernel_launch(void* const* d_in, const int* in_sizes, int n_in,
                              void* d_out, int out_size, void* d_ws, size_t ws_size,
                              hipStream_t stream) {
    const int* coords = (const int*)d_in[0];
    const float* feats = (const float*)d_in[1];
    float* out = (float*)d_out;
    float* vout = out;                          // [N_VERTS*10]
    float* outw = out + VOUT_WORDS;             // [N_CELLS*21]

    // d_ws: lastidx (8.4 MB) + blocksums (2 KB).
    int* lastidx = (int*)d_ws;
    unsigned int* blocksums = (unsigned int*)((char*)d_ws + sizeof(int) * (size_t)N_CELLS);

    // CSR scratch in the TAIL of outw; fully consumed by gather_finalize_tiled
    // which runs strictly before weights_fill overwrites outw.
    long scratch_words = (long)N_CELLS /*counts->cursors*/ + (N_CELLS + 1) /*starts*/
                       + N_VOX /*list*/ + 16;
    unsigned int* counts = (unsigned int*)(outw + (OUTW_WORDS - scratch_words));
    unsigned int* starts = counts + N_CELLS;            // [N_CELLS+1]
    unsigned int* list   = starts + (N_CELLS + 1);      // [N_VOX]

    init_kernel<<<(N_CELLS + 255) / 256, 256, 0, stream>>>(counts, lastidx);
    count_kernel<<<(N_VOX + 255) / 256, 256, 0, stream>>>(coords, counts, lastidx);
    scan1_kernel<<<SCAN_BLOCKS, 256, 0, stream>>>(counts, starts, blocksums);
    scan2_kernel<<<1, SCAN_BLOCKS, 0, stream>>>(blocksums);
    fixup_kernel<<<(N_CELLS + 255) / 256, 256, 0, stream>>>(starts, counts, blocksums);
    fill_kernel<<<(N_VOX + 255) / 256, 256, 0, stream>>>(coords, counts, list);
    {
        dim3 grid(17, 17, 17), block(8, 8, 8);
        gather_finalize_tiled<<<grid, block, 0, stream>>>(feats, starts, list, vout);
    }
    {
        long total = OUTW_WORDS;
        weights_fill<<<(int)((total + 255) / 256), 256, 0, stream>>>(feats, lastidx, outw);
    }
}